// Round 8
// baseline (10127.383 us; speedup 1.0000x reference)
//
#include <hip/hip_runtime.h>

typedef __attribute__((ext_vector_type(8))) short short8;
typedef __attribute__((ext_vector_type(4))) float f32x4;
typedef __attribute__((ext_vector_type(4))) int int4v;

#define HD 1024
#define BD 64
#define TD 512
#define BH 65536UL  // one h slot: 64*1024 ushorts (128 KB)
#define NSE 8       // export slot rotation depth == consumer fence period
#define NSL 4       // local slot rotation depth (WAR implied by recurrence wait)
#define NBLK 256    // 1 block/CU (proven co-residency + %8 XCD mapping)
#define FSTRIDE 32  // flag padding: 32 ints = 128 B = one line per WG

// ---------------- workspace layout (identical to R7's prep layout) ----------------
#define M4 4194304UL
#define OFF_WHH0 0UL
#define OFF_WIH1 (1UL * M4)
#define OFF_WHH1 (2UL * M4)
#define OFF_WIH2 (3UL * M4)
#define OFF_WHH2 (4UL * M4)
#define OFF_WOUT (5UL * M4)                 // 128 x 1024 (padded rows zeroed)
#define OFF_H0   (OFF_WOUT + 131072UL)      // export: [NSE][64][1024] per layer (sc1/MALL)
#define OFF_H1   (OFF_H0 + (NSE * BH))
#define OFF_H2   (OFF_H1 + (NSE * BH))
#define OFF_HL0  (OFF_H2 + (NSE * BH))      // local: [NSL][64][1024] per layer (own-XCD L2)
#define OFF_HL1  (OFF_HL0 + (NSL * BH))
#define OFF_HL2  (OFF_HL1 + (NSL * BH))
#define USHORT_TOTAL (OFF_HL2 + (NSL * BH)) // 23461888
#define FBYTE_BASE (USHORT_TOTAL * 2UL)     // 46923776
#define FOFF_C0 0UL                          // c stored [j][b] (transposed)
#define FOFF_C1 65536UL
#define FOFF_C2 131072UL
#define FOFF_B0 196608UL                     // combined biases b_ih+b_hh [4096]
#define FOFF_B1 200704UL
#define FOFF_B2 204800UL
#define FOFF_BOUT 208896UL                   // [128], pad zeroed
#define FOFF_FLAGS 209024UL                  // 7 arrays x 64 WGs x FSTRIDE ints
#define PREP_TOTAL 23685248UL

__device__ __forceinline__ unsigned short f2bf(float f) {
  union { float f; unsigned u; } v; v.f = f;
  unsigned r = v.u + 0x7fffu + ((v.u >> 16) & 1u);  // RNE
  return (unsigned short)(r >> 16);
}
__device__ __forceinline__ float sigmoidf_(float x) {
  return 1.0f / (1.0f + __expf(-x));
}
// LDS bank swizzle (unchanged).
__device__ __forceinline__ int sw(int gn, int b) {
  return gn * 64 + (b ^ (((gn & 7) << 2) | ((gn >> 3) & 3)));
}

// A-loads, two flavors:
//  SC0=true : L1-bypass (GLC heritage) -> served by own-XCD L2, which the
//             same-XCD producers update via plain write-through stores.
//             No fence needed (no cache level can go stale).
//  SC0=false: plain cached read of an sc1-exported buffer; freshness by
//             NSE-slot rotation + one acquire fence per 8-step window
//             (R4/R5/R6-validated per-address argument).
template <bool SC0>
__device__ __forceinline__ void gload16t(int4v& dst, const unsigned short* p) {
  if constexpr (SC0)
    asm volatile("global_load_dwordx4 %0, %1, off sc0" : "=v"(dst) : "v"(p));
  else
    asm volatile("global_load_dwordx4 %0, %1, off" : "=v"(dst) : "v"(p));
}
#define AWAIT_N(N, a0, a1, a2, a3) \
  asm volatile("s_waitcnt vmcnt(" #N ")" : "+v"(a0), "+v"(a1), "+v"(a2), "+v"(a3))

// ---------------- padded flags, two coherence domains ----------------
// flc[layer][wg]: plain store, sc0 poll -- intra-XCD via L2.
// fe [layer][wg], f3: sc1 store/poll -- cross-XCD via MALL.
// Remote/upstream waves poll 32-flag half-sets; WAR polls the full 64.
__device__ __forceinline__ void wr32(const int* f, int k, int lane) {   // sc1, 32-set
  const int* p = f + (lane & 31) * FSTRIDE;
  for (;;) {
    int v;
    asm volatile("global_load_dword %0, %1, off sc1" : "=v"(v) : "v"(p));
    asm volatile("s_waitcnt vmcnt(0)" : "+v"(v));
    if (__all(v >= k)) return;
    __builtin_amdgcn_s_sleep(2);
  }
}
// local 32-set: sc0 fast path + sc1 export-flag fallback (deadlock-proof:
// fe >= k implies the producer passed its local publish of the same step).
__device__ __forceinline__ void wl32(const int* fl, const int* fe, int k, int lane) {
  const int* pl = fl + (lane & 31) * FSTRIDE;
  const int* pe = fe + (lane & 31) * FSTRIDE;
  for (int s = 0;; ++s) {
    int v;
    asm volatile("global_load_dword %0, %1, off sc0" : "=v"(v) : "v"(pl));
    asm volatile("s_waitcnt vmcnt(0)" : "+v"(v));
    if (__all(v >= k)) return;
    if ((s & 63) == 63) {
      int u;
      asm volatile("global_load_dword %0, %1, off sc1" : "=v"(u) : "v"(pe));
      asm volatile("s_waitcnt vmcnt(0)" : "+v"(u));
      if (__all(u >= k)) return;
    }
    __builtin_amdgcn_s_sleep(1);
  }
}
__device__ __forceinline__ void wc64(const int* f, int k, int lane) {   // sc1, 64-set
  const int* p = f + lane * FSTRIDE;
  for (;;) {
    int v;
    asm volatile("global_load_dword %0, %1, off sc1" : "=v"(v) : "v"(p));
    asm volatile("s_waitcnt vmcnt(0)" : "+v"(v));
    if (__all(v >= k)) return;
    __builtin_amdgcn_s_sleep(4);
  }
}

// ---------------- prep ----------------
__global__ void prep_kernel(const float* __restrict__ Whh0, const float* __restrict__ Wih1,
                            const float* __restrict__ Whh1, const float* __restrict__ Wih2,
                            const float* __restrict__ Whh2, const float* __restrict__ Wout,
                            const float* __restrict__ bih0, const float* __restrict__ bhh0,
                            const float* __restrict__ bih1, const float* __restrict__ bhh1,
                            const float* __restrict__ bih2, const float* __restrict__ bhh2,
                            const float* __restrict__ bout, void* wsv) {
  unsigned short* u = (unsigned short*)wsv;
  float* fr = (float*)((char*)wsv + FBYTE_BASE);
  int* fi = (int*)fr;
  size_t stride = (size_t)gridDim.x * blockDim.x;
  for (size_t i = (size_t)blockIdx.x * blockDim.x + threadIdx.x; i < PREP_TOTAL; i += stride) {
    if (i < 20971520UL) {
      size_t which = i >> 22;
      size_t off = i & (M4 - 1UL);
      const float* src = (which == 0) ? Whh0 : (which == 1) ? Wih1 :
                         (which == 2) ? Whh1 : (which == 3) ? Wih2 : Whh2;
      u[i] = f2bf(src[off]);
    } else if (i < 21102592UL) {
      size_t k = i - 20971520UL;
      size_t o = k >> 10, kk = k & 1023UL;
      u[i] = (o < 121) ? f2bf(Wout[o * 1024UL + kk]) : (unsigned short)0;
    } else if (i < USHORT_TOTAL) {
      u[i] = 0;                                   // zero export + local h slots
    } else {
      size_t k = i - USHORT_TOTAL;
      if (k < 196608UL) {
        fr[k] = 0.0f;                             // zero c0,c1,c2
      } else if (k < 208896UL) {
        size_t l = (k - 196608UL) >> 12, n = k & 4095UL;
        const float* bi = (l == 0) ? bih0 : (l == 1) ? bih1 : bih2;
        const float* bh = (l == 0) ? bhh0 : (l == 1) ? bhh1 : bhh2;
        fr[FOFF_B0 + l * 4096UL + n] = bi[n] + bh[n];
      } else if (k < 209024UL) {
        size_t kk = k - 208896UL;
        fr[FOFF_BOUT + kk] = (kk < 121) ? bout[kk] : 0.0f;
      } else {
        size_t q = k - 209024UL;                  // 7 x 2048 flag ints
        size_t a = q >> 11;                       // fe0,fe1,fe2,f3,flc0,flc1,flc2
        size_t wg = (q & 2047UL) >> 5;
        fi[FOFF_FLAGS + q] = (a == 3 && wg >= 2) ? (1 << 29) : 0;
      }
    }
  }
}

// ---------------- GEMM slice: register B, 6-deep explicit-vmcnt pipelined A ----------------
template <int NK, bool SC0>
__device__ __forceinline__ void gemm_bw(const unsigned short* __restrict__ arow,
                                        const short8 (&bw)[NK][4],
                                        f32x4 (&acc)[4][4]) {
  static_assert(NK >= 6, "pipeline depth");
  int4v ap[6][4];
#pragma unroll
  for (int g = 0; g < 6; ++g)
#pragma unroll
    for (int mt = 0; mt < 4; ++mt)
      gload16t<SC0>(ap[g][mt], arow + mt * 16 * HD + g * 32);
#pragma unroll
  for (int k = 0; k < NK; ++k) {
    const int s = k % 6;
    if (k <= NK - 6)          { AWAIT_N(20, ap[s][0], ap[s][1], ap[s][2], ap[s][3]); }
    else if (NK - 1 - k == 4) { AWAIT_N(16, ap[s][0], ap[s][1], ap[s][2], ap[s][3]); }
    else if (NK - 1 - k == 3) { AWAIT_N(12, ap[s][0], ap[s][1], ap[s][2], ap[s][3]); }
    else if (NK - 1 - k == 2) { AWAIT_N(8,  ap[s][0], ap[s][1], ap[s][2], ap[s][3]); }
    else if (NK - 1 - k == 1) { AWAIT_N(4,  ap[s][0], ap[s][1], ap[s][2], ap[s][3]); }
    else                      { AWAIT_N(0,  ap[s][0], ap[s][1], ap[s][2], ap[s][3]); }
#pragma unroll
    for (int mt = 0; mt < 4; ++mt) {
      short8 a = *(short8*)&ap[s][mt];
#pragma unroll
      for (int ns = 0; ns < 4; ++ns)
        acc[ns][mt] = __builtin_amdgcn_mfma_f32_16x16x32_bf16(a, bw[k][ns], acc[ns][mt], 0, 0, 0);
    }
    if (k + 6 < NK) {
#pragma unroll
      for (int mt = 0; mt < 4; ++mt)
        gload16t<SC0>(ap[s][mt], arow + mt * 16 * HD + (k + 6) * 32);
    }
  }
}

// ---------------- layer driver: dual-path h (local L2 half + MALL half) ----------------
// Layer spans an XCD pair: even XCD hosts wgl 0..31 (produces h[0..511]),
// odd XCD hosts wgl 32..63 (h[512..1023]) -- R5-confirmed %8 mapping.
// A wave reading k-range [k0beg,k0beg+512) is LOCAL iff its half was produced
// on its own XCD: isLoc = ((k0beg>=512) == (wgl>=32)).
//  local : sc0 loads of hloc (plain-stored, 4-slot), flc flags (plain/sc0).
//  remote/upstream: cached loads of hexp (sc1-stored, 8-slot) + 1/8 fence,
//                   fe flags (sc1).
// Publish: [local stores -> vmcnt0 -> bar -> flc=t+1] then
//          [export sc1 stores -> vmcnt0 -> bar -> fe=t+1].
// WAR: export slot reuse gated by fCons (downstream progress) >= t-(NSE-1),
// polled by w0 (same-layer readers are implied >= t by the recurrence wait).
// Local slot WAR implied: producer's own recurrence wait guarantees all own
// WGs >= t, so nobody can still be reading h[t-NSL].
template <bool L0L>
__device__ __forceinline__ void run_layer(
    int wgl, int tid,
    const unsigned short* __restrict__ hin,      // upstream EXPORT (null for L0)
    unsigned short* __restrict__ hloc,           // own local h [NSL][BH]
    unsigned short* __restrict__ hexp,           // own export h [NSE][BH]
    float* __restrict__ c,                       // [1024][64] fp32 transposed
    const unsigned short* __restrict__ Wih,      // null for L0
    const unsigned short* __restrict__ Whh,
    const float* __restrict__ bias,
    const float* __restrict__ strokes,           // L0 only
    const float* __restrict__ Wih0,              // L0 only, fp32 [4096][3]
    float* gbuf,
    int* fLoc, int* fExp, const int* fProd, const int* fCons) {
  constexpr int NK = L0L ? 8 : 16;
  const int lane = tid & 63;
  const int w = tid >> 6;
  const int nl = lane & 15;
  const int kq8 = (lane >> 4) << 3;

  const unsigned short* Wm;
  int k0beg;
  bool useHin;
  if (L0L) { Wm = Whh; k0beg = w * 256; useHin = false; }
  else     { Wm = (w < 2) ? Wih : Whh; k0beg = (w & 1) * 512; useHin = (w < 2); }

  short8 bw[NK][4];
#pragma unroll
  for (int ns = 0; ns < 4; ++ns) {
    int jgl = wgl * 16 + ns * 4 + (nl >> 2);
    int row = (nl & 3) * HD + jgl;                 // gate-major weight row
    const unsigned short* wr = Wm + (size_t)row * HD + kq8 + k0beg;
#pragma unroll
    for (int k = 0; k < NK; ++k) bw[k][ns] = *(const short8*)(wr + k * 32);
  }

  const bool halfB = (k0beg >= 512);               // which h-half this wave reads
  const bool isLoc = (!useHin) && (halfB == (wgl >= 32));
  const int fbase = (halfB ? 32 : 0) * FSTRIDE;    // flag offset of that half
  const bool cachedReader = useHin || !isLoc;      // needs the 1/8 fence

  const int bb = (lane >> 4) << 2;
  float* gs = gbuf + w * 4096;

  for (int t = 0; t < TD; ++t) {
    // ---- per-wave decoupled waits ----
    if (useHin) {                                  // non-L0 w0/w1: upstream half
      if (w == 0) wc64(fCons, t - (NSE - 1), lane);    // export WAR (slack path)
      wr32(fProd + fbase, t + 1, lane);
    } else {                                       // recurrence waves
      if (L0L && w == 0) wc64(fCons, t - (NSE - 1), lane);
      if (t > 0) {
        if (isLoc) wl32(fLoc + fbase, fExp + fbase, t, lane);
        else       wr32(fExp + fbase, t, lane);
      }
    }
    // Export-slot reuse invalidate, once per NSE steps, cached readers only.
    if (cachedReader && (t & (NSE - 1)) == 0)
      __builtin_amdgcn_fence(__ATOMIC_ACQUIRE, "agent");

    const unsigned short* A;
    if (useHin)     A = hin  + (size_t)(t & (NSE - 1)) * BH;
    else if (isLoc) A = hloc + (size_t)((t - 1) & (NSL - 1)) * BH;
    else            A = hexp + (size_t)((t - 1) & (NSE - 1)) * BH;
    const unsigned short* arow = A + nl * HD + kq8 + k0beg;

    f32x4 acc[4][4];
    const f32x4 z4 = {0.f, 0.f, 0.f, 0.f};
#pragma unroll
    for (int ns = 0; ns < 4; ++ns)
#pragma unroll
      for (int mt = 0; mt < 4; ++mt) acc[ns][mt] = z4;

    if (isLoc) gemm_bw<NK, true >(arow, bw, acc);
    else       gemm_bw<NK, false>(arow, bw, acc);

#pragma unroll
    for (int ns = 0; ns < 4; ++ns) {
      int gn = ns * 16 + nl;
#pragma unroll
      for (int mt = 0; mt < 4; ++mt)
#pragma unroll
        for (int r = 0; r < 4; ++r)
          gs[sw(gn, mt * 16 + bb + r)] = acc[ns][mt][r];
    }
    __syncthreads();

    // ---- epilogue: compute h into registers ----
    unsigned pkv[2];
    int hoff[2];
#pragma unroll
    for (int it = 0; it < 2; ++it) {
      int item = it * 256 + tid;
      int jp = item >> 6;          // 0..7 pair of j
      int b = item & 63;
      unsigned hv[2];
#pragma unroll
      for (int u2 = 0; u2 < 2; ++u2) {
        int jj = jp * 2 + u2;
        int j = wgl * 16 + jj;
        float p[4];
#pragma unroll
        for (int g = 0; g < 4; ++g) {
          int a = sw(jj * 4 + g, b);
          p[g] = gbuf[a] + gbuf[4096 + a] + gbuf[8192 + a] + gbuf[12288 + a] + bias[g * HD + j];
        }
        if (L0L) {
          const float* xr = strokes + ((size_t)b * TD + t) * 3;
          float x0 = xr[0], x1 = xr[1], x2 = xr[2];
#pragma unroll
          for (int g = 0; g < 4; ++g) {
            const float* wr = Wih0 + (size_t)(g * HD + j) * 3;
            p[g] += x0 * wr[0] + x1 * wr[1] + x2 * wr[2];
          }
        }
        float iv = sigmoidf_(p[0]);
        float fv = sigmoidf_(p[1]);
        float gv = tanhf(p[2]);
        float ov = sigmoidf_(p[3]);
        int ci = j * BD + b;       // CU-private, normal cached RMW
        float cn = fv * c[ci] + iv * gv;
        c[ci] = cn;
        hv[u2] = (unsigned)f2bf(ov * tanhf(cn));
      }
      pkv[it] = hv[0] | (hv[1] << 16);
      hoff[it] = b * HD + wgl * 16 + jp * 2;
    }

    // ---- phase A: local copy (own L2) + fast flag ----
    unsigned short* hl = hloc + (size_t)(t & (NSL - 1)) * BH;
#pragma unroll
    for (int it = 0; it < 2; ++it)
      *(unsigned*)(hl + hoff[it]) = pkv[it];       // plain write-through store
    asm volatile("s_waitcnt vmcnt(0)" ::: "memory");
    __syncthreads();
    if (tid == 0) {
      int tv = t + 1;
      asm volatile("global_store_dword %0, %1, off"
                   :: "v"(fLoc + wgl * FSTRIDE), "v"(tv) : "memory");
    }
    // ---- phase B: export copy (MALL) + slow flag ----
    unsigned short* he = hexp + (size_t)(t & (NSE - 1)) * BH;
#pragma unroll
    for (int it = 0; it < 2; ++it)
      __hip_atomic_store((unsigned*)(he + hoff[it]), pkv[it],
                         __ATOMIC_RELAXED, __HIP_MEMORY_SCOPE_AGENT);
    asm volatile("s_waitcnt vmcnt(0)" ::: "memory");
    __syncthreads();
    if (tid == 0) {
      int tv = t + 1;
      asm volatile("global_store_dword %0, %1, off sc1"
                   :: "v"(fExp + wgl * FSTRIDE), "v"(tv) : "memory");
    }
  }
}

// ---------------- output projection driver (2 WGs, XCD 6) ----------------
__device__ __forceinline__ void run_out(
    int wgo, int tid,
    const unsigned short* __restrict__ h2exp,
    const unsigned short* __restrict__ Wo,   // bf16 [128][1024] padded
    const float* __restrict__ bo,
    float* __restrict__ outp, float* gbuf, int* fOwn, const int* fProd) {
  const int lane = tid & 63;
  const int w = tid >> 6;
  const int nl = lane & 15;
  const int kq8 = (lane >> 4) << 3;
  const int k0beg = w * 256;

  short8 bw[8][4];
#pragma unroll
  for (int ns = 0; ns < 4; ++ns) {
    int o = wgo * 64 + ns * 16 + nl;
    const unsigned short* wr = Wo + (size_t)o * HD + kq8 + k0beg;
#pragma unroll
    for (int k = 0; k < 8; ++k) bw[k][ns] = *(const short8*)(wr + k * 32);
  }

  const int bb = (lane >> 4) << 2;
  float* gs = gbuf + w * 4096;

  for (int t = 0; t < TD; ++t) {
    wc64(fProd, t + 1, lane);                    // h2 export for step t published
    if ((t & (NSE - 1)) == 0) __builtin_amdgcn_fence(__ATOMIC_ACQUIRE, "agent");

    const unsigned short* arow = h2exp + (size_t)(t & (NSE - 1)) * BH + nl * HD + kq8 + k0beg;

    f32x4 acc[4][4];
    const f32x4 z4 = {0.f, 0.f, 0.f, 0.f};
#pragma unroll
    for (int ns = 0; ns < 4; ++ns)
#pragma unroll
      for (int mt = 0; mt < 4; ++mt) acc[ns][mt] = z4;

    gemm_bw<8, false>(arow, bw, acc);

#pragma unroll
    for (int ns = 0; ns < 4; ++ns) {
      int gn = ns * 16 + nl;
#pragma unroll
      for (int mt = 0; mt < 4; ++mt)
#pragma unroll
        for (int r = 0; r < 4; ++r)
          gs[sw(gn, mt * 16 + bb + r)] = acc[ns][mt][r];
    }
    __syncthreads();

#pragma unroll
    for (int it = 0; it < 16; ++it) {
      int item = it * 256 + tid;
      int ol = item >> 6;
      int b = item & 63;
      int o = wgo * 64 + ol;
      int a = sw(ol, b);
      float v = gbuf[a] + gbuf[4096 + a] + gbuf[8192 + a] + gbuf[12288 + a] + bo[o];
      if (o < 121) outp[((size_t)b * TD + t) * 121 + o] = v;
    }
    // A-reads of h2[t] retired (gemm drains to vmcnt 0) -> WAR signal for L2.
    asm volatile("s_waitcnt vmcnt(0)" ::: "memory");
    __syncthreads();
    if (tid == 0) {
      int tv = t + 1;
      asm volatile("global_store_dword %0, %1, off sc1"
                   :: "v"(fOwn + wgo * FSTRIDE), "v"(tv) : "memory");
    }
  }
}

// ---------------- main kernel ----------------
// Proven R5/R6 placement: 256 blocks, 1/CU; XCD = blockIdx&7.
// XCDs 0,1 -> layer0 (wgl = ((xcd&1)<<5)+slot); 2,3 -> layer1; 4,5 -> layer2;
// XCD 6 slots 0,1 -> out-proj; everything else exits.
__global__ void __launch_bounds__(256, 1)
lstm_main(const float* __restrict__ strokes, const float* __restrict__ Wih0,
          float* __restrict__ outp, void* __restrict__ wsv) {
  __shared__ float gbuf[16384];  // 64 KB: 4 K-slices x [64 gn][64 b]
  unsigned short* u = (unsigned short*)wsv;
  float* fr = (float*)((char*)wsv + FBYTE_BASE);
  int* flags = (int*)fr + FOFF_FLAGS;
  int* fe0 = flags;              // export progress, sc1 (cross-XCD)
  int* fe1 = flags + 2048;
  int* fe2 = flags + 4096;
  int* f3  = flags + 6144;       // out progress, sc1 (2 real + 62 preset huge)
  int* fl0 = flags + 8192;       // local progress, plain store / sc0 poll
  int* fl1 = flags + 10240;
  int* fl2 = flags + 12288;

  const int xcd = blockIdx.x & 7;
  const int slot = blockIdx.x >> 3;   // 0..31
  const int tid = threadIdx.x;

  if (xcd < 2) {
    int wgl = ((xcd & 1) << 5) + slot;
    run_layer<true>(wgl, tid, nullptr, u + OFF_HL0, u + OFF_H0, fr + FOFF_C0,
                    nullptr, u + OFF_WHH0, fr + FOFF_B0, strokes, Wih0, gbuf,
                    fl0, fe0, nullptr, fe1);
  } else if (xcd < 4) {
    int wgl = ((xcd & 1) << 5) + slot;
    run_layer<false>(wgl, tid, u + OFF_H0, u + OFF_HL1, u + OFF_H1, fr + FOFF_C1,
                     u + OFF_WIH1, u + OFF_WHH1, fr + FOFF_B1, nullptr, nullptr, gbuf,
                     fl1, fe1, fe0, fe2);
  } else if (xcd < 6) {
    int wgl = ((xcd & 1) << 5) + slot;
    run_layer<false>(wgl, tid, u + OFF_H1, u + OFF_HL2, u + OFF_H2, fr + FOFF_C2,
                     u + OFF_WIH2, u + OFF_WHH2, fr + FOFF_B2, nullptr, nullptr, gbuf,
                     fl2, fe2, fe1, f3);
  } else if (xcd == 6 && slot < 2) {
    run_out(slot, tid, u + OFF_H2, u + OFF_WOUT, fr + FOFF_BOUT, outp, gbuf,
            f3, fe2);
  }
  // else: idle block, exit immediately
}

extern "C" void kernel_launch(void* const* d_in, const int* in_sizes, int n_in,
                              void* d_out, int out_size, void* d_ws, size_t ws_size,
                              hipStream_t stream) {
  const float* strokes = (const float*)d_in[0];
  const float* Wih0 = (const float*)d_in[1];
  const float* Whh0 = (const float*)d_in[2];
  const float* bih0 = (const float*)d_in[3];
  const float* bhh0 = (const float*)d_in[4];
  const float* Wih1 = (const float*)d_in[5];
  const float* Whh1 = (const float*)d_in[6];
  const float* bih1 = (const float*)d_in[7];
  const float* bhh1 = (const float*)d_in[8];
  const float* Wih2 = (const float*)d_in[9];
  const float* Whh2 = (const float*)d_in[10];
  const float* bih2 = (const float*)d_in[11];
  const float* bhh2 = (const float*)d_in[12];
  const float* Wout = (const float*)d_in[13];
  const float* bout = (const float*)d_in[14];
  float* outp = (float*)d_out;

  hipLaunchKernelGGL(prep_kernel, dim3(4096), dim3(256), 0, stream,
                     Whh0, Wih1, Whh1, Wih2, Whh2, Wout,
                     bih0, bhh0, bih1, bhh1, bih2, bhh2, bout, d_ws);

  hipLaunchKernelGGL(lstm_main, dim3(NBLK), dim3(256), 0, stream,
                     strokes, Wih0, outp, d_ws);
}

// Round 9
// 5309.706 us; speedup vs baseline: 1.9073x; 1.9073x over previous
//
#include <hip/hip_runtime.h>

typedef __attribute__((ext_vector_type(8))) short short8;
typedef __attribute__((ext_vector_type(4))) float f32x4;
typedef __attribute__((ext_vector_type(4))) int int4v;

#define HD 1024
#define BD 64
#define TD 512
#define BH 65536UL  // one h slot: 64 wg x 64 b x 16 j ushorts (128 KB)
#define NS 16       // h slot rotation depth == fence period
#define NBLK 256    // 1 block/CU; XCD-partitioned mapping inside
#define FSTRIDE 32  // flag padding: 32 ints = 128 B = one line per WG

// ---------------- workspace layout (identical to R6) ----------------
#define M4 4194304UL
#define OFF_WHH0 0UL
#define OFF_WIH1 (1UL * M4)
#define OFF_WHH1 (2UL * M4)
#define OFF_WIH2 (3UL * M4)
#define OFF_WHH2 (4UL * M4)
#define OFF_WOUT (5UL * M4)                 // 128 x 1024 (padded rows zeroed)
#define OFF_H0   (OFF_WOUT + 131072UL)      // [NS][wg][b][16j] per layer (chunked!)
#define OFF_H1   (OFF_H0 + (NS * BH))
#define OFF_H2   (OFF_H1 + (NS * BH))
#define USHORT_TOTAL (OFF_H2 + (NS * BH))   // 24248320
#define FBYTE_BASE (USHORT_TOTAL * 2UL)
#define FOFF_C0 0UL                          // (unused now; kept for prep layout)
#define FOFF_B0 196608UL                     // combined biases b_ih+b_hh [4096]
#define FOFF_B1 200704UL
#define FOFF_B2 204800UL
#define FOFF_BOUT 208896UL                   // [128], pad zeroed
#define FOFF_FLAGS 209024UL                  // 4 arrays x 64 WGs x FSTRIDE ints
#define PREP_TOTAL 24465536UL

__device__ __forceinline__ unsigned short f2bf(float f) {
  union { float f; unsigned u; } v; v.f = f;
  unsigned r = v.u + 0x7fffu + ((v.u >> 16) & 1u);  // RNE
  return (unsigned short)(r >> 16);
}
__device__ __forceinline__ float sigmoidf_(float x) {
  return 1.0f / (1.0f + __expf(-x));
}
// fast tanh via exp2-based __expf: tanh(x) = 1 - 2/(e^(2x)+1).
// err ~1e-5 << bf16 ulp of h (~4e-3); saturates correctly at +-1.
__device__ __forceinline__ float tanhf_(float x) {
  float e = __expf(x + x);
  return 1.0f - 2.0f / (e + 1.0f);
}
// LDS bank swizzle (unchanged).
__device__ __forceinline__ int sw(int gn, int b) {
  return gn * 64 + (b ^ (((gn & 7) << 2) | ((gn >> 3) & 3)));
}

// A-matrix load: plain cached 16B load (L2-served under the XCD partition).
// Coherence contract (HW-validated R4/R5/R6): producers sc1-write-through h
// and drain vmcnt(0) before the relaxed flag store; NS=16 slot rotation + one
// acquire fence per 16-step window prevents any stale cache line from
// serving a current-slot read.
__device__ __forceinline__ void gload16(int4v& dst, const unsigned short* p) {
  asm volatile("global_load_dwordx4 %0, %1, off" : "=v"(dst) : "v"(p));
}
#define AWAIT_N(N, a0, a1, a2, a3) \
  asm volatile("s_waitcnt vmcnt(" #N ")" : "+v"(a0), "+v"(a1), "+v"(a2), "+v"(a3))

// ---------------- padded per-WG progress flags (R6 scheme) ----------------
__device__ __forceinline__ void wait1p(const int* fa, int ka, int lane) {
  const int* pa = fa + lane * FSTRIDE;
  for (;;) {
    int va;
    asm volatile("global_load_dword %0, %1, off sc1" : "=v"(va) : "v"(pa));
    asm volatile("s_waitcnt vmcnt(0)" : "+v"(va));
    if (__all(va >= ka)) return;
    __builtin_amdgcn_s_sleep(2);   // recurrence-critical: short sleep
  }
}
__device__ __forceinline__ void wait2p(const int* fa, int ka, const int* fb, int kb, int lane) {
  const int* pa = fa + lane * FSTRIDE;
  const int* pb = fb + lane * FSTRIDE;
  for (;;) {
    int va, vb;
    asm volatile("global_load_dword %0, %1, off sc1" : "=v"(va) : "v"(pa));
    asm volatile("global_load_dword %0, %1, off sc1" : "=v"(vb) : "v"(pb));
    asm volatile("s_waitcnt vmcnt(0)" : "+v"(va), "+v"(vb));
    if (__all(va >= ka) && __all(vb >= kb)) return;
    __builtin_amdgcn_s_sleep(8);
  }
}
__device__ __forceinline__ void mb_store(int* m, int t, int lane) {
  if (lane == 0)
    __hip_atomic_store(m, t, __ATOMIC_RELEASE, __HIP_MEMORY_SCOPE_WORKGROUP);
}
__device__ __forceinline__ void mb_spin(const int* m, int t) {
  while (__hip_atomic_load(m, __ATOMIC_ACQUIRE, __HIP_MEMORY_SCOPE_WORKGROUP) < t)
    __builtin_amdgcn_s_sleep(1);
}

// ---------------- prep (identical byte layout to R6) ----------------
__global__ void prep_kernel(const float* __restrict__ Whh0, const float* __restrict__ Wih1,
                            const float* __restrict__ Whh1, const float* __restrict__ Wih2,
                            const float* __restrict__ Whh2, const float* __restrict__ Wout,
                            const float* __restrict__ bih0, const float* __restrict__ bhh0,
                            const float* __restrict__ bih1, const float* __restrict__ bhh1,
                            const float* __restrict__ bih2, const float* __restrict__ bhh2,
                            const float* __restrict__ bout, void* wsv) {
  unsigned short* u = (unsigned short*)wsv;
  float* fr = (float*)((char*)wsv + FBYTE_BASE);
  int* fi = (int*)fr;
  size_t stride = (size_t)gridDim.x * blockDim.x;
  for (size_t i = (size_t)blockIdx.x * blockDim.x + threadIdx.x; i < PREP_TOTAL; i += stride) {
    if (i < 20971520UL) {
      size_t which = i >> 22;
      size_t off = i & (M4 - 1UL);
      const float* src = (which == 0) ? Whh0 : (which == 1) ? Wih1 :
                         (which == 2) ? Whh1 : (which == 3) ? Wih2 : Whh2;
      u[i] = f2bf(src[off]);
    } else if (i < 21102592UL) {
      size_t k = i - 20971520UL;
      size_t o = k >> 10, kk = k & 1023UL;
      u[i] = (o < 121) ? f2bf(Wout[o * 1024UL + kk]) : (unsigned short)0;
    } else if (i < 24248320UL) {
      u[i] = 0;                                   // zero all NS h slots x 3 layers
    } else if (i < 24444928UL) {
      fr[i - 24248320UL] = 0.0f;                  // legacy c region (unused)
    } else if (i < 24457216UL) {
      size_t k = i - 24444928UL;
      size_t l = k >> 12, n = k & 4095UL;
      const float* bi = (l == 0) ? bih0 : (l == 1) ? bih1 : bih2;
      const float* bh = (l == 0) ? bhh0 : (l == 1) ? bhh1 : bhh2;
      fr[FOFF_B0 + l * 4096UL + n] = bi[n] + bh[n];
    } else if (i < 24457344UL) {
      size_t k = i - 24457216UL;
      fr[FOFF_BOUT + k] = (k < 121) ? bout[k] : 0.0f;
    } else {
      size_t k = i - 24457344UL;                  // 8192 padded flag ints
      size_t a = k >> 11;                         // array 0..3
      size_t wg = (k & 2047UL) >> 5;              // WG slot within array
      fi[FOFF_FLAGS + k] = (a < 3 || wg < 2) ? 0 : (1 << 29);
    }
  }
}

// ---------------- GEMM slice over CHUNKED h: [wg][b][16j] ----------------
// Lane reads k = k0beg + g*32 + kq8 for batch rows nl + mt*16.
// Chunked address (ushorts): wgk*1024 + brow*16 + (k&15), with
// wgk = (k>>4). Per-lane base arow = A + ((k0beg>>4)+(kq8>>4))*1024
// + nl*16 + (kq8&8); then mt stride = 256, g stride = 2048.
template <int NK>
__device__ __forceinline__ void gemm_bw(const unsigned short* __restrict__ arow,
                                        const short8 (&bw)[NK][4],
                                        f32x4 (&acc)[4][4]) {
  static_assert(NK >= 6, "pipeline depth");
  int4v ap[6][4];
#pragma unroll
  for (int g = 0; g < 6; ++g)
#pragma unroll
    for (int mt = 0; mt < 4; ++mt)
      gload16(ap[g][mt], arow + mt * 256 + g * 2048);
#pragma unroll
  for (int k = 0; k < NK; ++k) {
    const int s = k % 6;
    if (k <= NK - 6)          { AWAIT_N(20, ap[s][0], ap[s][1], ap[s][2], ap[s][3]); }
    else if (NK - 1 - k == 4) { AWAIT_N(16, ap[s][0], ap[s][1], ap[s][2], ap[s][3]); }
    else if (NK - 1 - k == 3) { AWAIT_N(12, ap[s][0], ap[s][1], ap[s][2], ap[s][3]); }
    else if (NK - 1 - k == 2) { AWAIT_N(8,  ap[s][0], ap[s][1], ap[s][2], ap[s][3]); }
    else if (NK - 1 - k == 1) { AWAIT_N(4,  ap[s][0], ap[s][1], ap[s][2], ap[s][3]); }
    else                      { AWAIT_N(0,  ap[s][0], ap[s][1], ap[s][2], ap[s][3]); }
#pragma unroll
    for (int mt = 0; mt < 4; ++mt) {
      short8 a = *(short8*)&ap[s][mt];
#pragma unroll
      for (int ns = 0; ns < 4; ++ns)
        acc[ns][mt] = __builtin_amdgcn_mfma_f32_16x16x32_bf16(a, bw[k][ns], acc[ns][mt], 0, 0, 0);
    }
    if (k + 6 < NK) {
#pragma unroll
      for (int mt = 0; mt < 4; ++mt)
        gload16(ap[s][mt], arow + mt * 256 + (k + 6) * 2048);
    }
  }
}

// ---------------- persistent-weight layer driver (R6 sync, chunked h, reg-c) ----------------
template <bool L0L>
__device__ __forceinline__ void run_layer(
    int wgl, int tid,
    const unsigned short* __restrict__ hinbase,  // upstream h (NS slots), null for L0
    unsigned short* __restrict__ hbase,          // own h (NS slots)
    const unsigned short* __restrict__ Wih,      // null for L0
    const unsigned short* __restrict__ Whh,
    const float* __restrict__ bias,
    const float* __restrict__ strokes,           // L0 only
    const float* __restrict__ Wih0,              // L0 only, fp32 [4096][3]
    float* gbuf, int* mb, int* fOwn, const int* fProd, const int* fCons) {
  constexpr int NK = L0L ? 8 : 16;
  const int lane = tid & 63;
  const int w = tid >> 6;
  const int nl = lane & 15;
  const int kq8 = (lane >> 4) << 3;

  const unsigned short* Wm;
  int k0beg;
  bool useHin;
  if (L0L) { Wm = Whh; k0beg = w * 256; useHin = false; }
  else     { Wm = (w < 2) ? Wih : Whh; k0beg = (w & 1) * 512; useHin = (w < 2); }

  short8 bw[NK][4];
#pragma unroll
  for (int ns = 0; ns < 4; ++ns) {
    int jgl = wgl * 16 + ns * 4 + (nl >> 2);
    int row = (nl & 3) * HD + jgl;                 // gate-major weight row
    const unsigned short* wr = Wm + (size_t)row * HD + kq8 + k0beg;
#pragma unroll
    for (int k = 0; k < NK; ++k) bw[k][ns] = *(const short8*)(wr + k * 32);
  }

  // per-lane chunked-A base offset (ushorts): wg-chunk + batch row + j-within
  const int aoff = ((k0beg >> 4) + (kq8 >> 4)) * 1024 + nl * 16 + (kq8 & 8);

  const int bb = (lane >> 4) << 2;
  float* gs = gbuf + w * 4096;

  // c state: thread-private, fixed (j,b) across t -> pure registers.
  float cr0 = 0.f, cr1 = 0.f, cr2 = 0.f, cr3 = 0.f;

  for (int t = 0; t < TD; ++t) {
    // ---- sync: 2 global pollers + 2 LDS spinners (R6 scheme) ----
    if (L0L) {
      if (t > 0) {
        if (w == 0)      { wait2p(fOwn, t, fCons, t - (NS - 1), lane); mb_store(mb + 0, t, lane); }
        else if (w == 1) { mb_spin(mb + 0, t); }
        else if (w == 2) { wait1p(fOwn, t, lane); mb_store(mb + 1, t, lane); }
        else             { mb_spin(mb + 1, t); }
      }
    } else {
      if (w == 0) {
        if (t > 0) wait2p(fProd, t + 1, fCons, t - (NS - 1), lane);
        else       wait1p(fProd, 1, lane);
        mb_store(mb + 0, t, lane);
      } else if (w == 1) {
        mb_spin(mb + 0, t);
      } else if (w == 2) {
        if (t > 0) { wait1p(fOwn, t, lane); mb_store(mb + 1, t, lane); }
      } else {
        if (t > 0) mb_spin(mb + 1, t);
      }
    }
    // Slot-reuse invalidate, once per NS steps.
    if ((t & (NS - 1)) == 0) __builtin_amdgcn_fence(__ATOMIC_ACQUIRE, "agent");

    const unsigned short* A = useHin ? (hinbase + (size_t)(t & (NS - 1)) * BH)
                                     : (hbase + (size_t)((t - 1) & (NS - 1)) * BH);
    const unsigned short* arow = A + aoff;

    f32x4 acc[4][4];
    const f32x4 z4 = {0.f, 0.f, 0.f, 0.f};
#pragma unroll
    for (int ns = 0; ns < 4; ++ns)
#pragma unroll
      for (int mt = 0; mt < 4; ++mt) acc[ns][mt] = z4;

    gemm_bw<NK>(arow, bw, acc);

#pragma unroll
    for (int ns = 0; ns < 4; ++ns) {
      int gn = ns * 16 + nl;
#pragma unroll
      for (int mt = 0; mt < 4; ++mt)
#pragma unroll
        for (int r = 0; r < 4; ++r)
          gs[sw(gn, mt * 16 + bb + r)] = acc[ns][mt][r];
    }
    __syncthreads();  // gbuf ready; also orders h-stores after w0's WAR check

    unsigned short* hout = hbase + (size_t)(t & (NS - 1)) * BH;
#pragma unroll
    for (int it = 0; it < 2; ++it) {
      int item = it * 256 + tid;
      int jp = item >> 6;          // 0..7 pair of j
      int b = item & 63;
      unsigned hv[2];
#pragma unroll
      for (int u2 = 0; u2 < 2; ++u2) {
        int jj = jp * 2 + u2;
        int j = wgl * 16 + jj;
        float p[4];
#pragma unroll
        for (int g = 0; g < 4; ++g) {
          int a = sw(jj * 4 + g, b);
          p[g] = gbuf[a] + gbuf[4096 + a] + gbuf[8192 + a] + gbuf[12288 + a] + bias[g * HD + j];
        }
        if (L0L) {
          const float* xr = strokes + ((size_t)b * TD + t) * 3;
          float x0 = xr[0], x1 = xr[1], x2 = xr[2];
#pragma unroll
          for (int g = 0; g < 4; ++g) {
            const float* wr = Wih0 + (size_t)(g * HD + j) * 3;
            p[g] += x0 * wr[0] + x1 * wr[1] + x2 * wr[2];
          }
        }
        float iv = sigmoidf_(p[0]);
        float fv = sigmoidf_(p[1]);
        float gv = tanhf_(p[2]);
        float ov = sigmoidf_(p[3]);
        float cold = (it == 0) ? (u2 == 0 ? cr0 : cr1) : (u2 == 0 ? cr2 : cr3);
        float cn = fv * cold + iv * gv;
        if (it == 0) { if (u2 == 0) cr0 = cn; else cr1 = cn; }
        else         { if (u2 == 0) cr2 = cn; else cr3 = cn; }
        hv[u2] = (unsigned)f2bf(ov * tanhf_(cn));
      }
      unsigned packed = hv[0] | (hv[1] << 16);
      // chunked layout: [wg][b][16j] -- whole 128B line owned by THIS WG.
      // sc1 write-through: MALL is the coherence point consumers fetch from.
      __hip_atomic_store((unsigned*)(hout + (size_t)wgl * 1024 + b * 16 + jp * 2), packed,
                         __ATOMIC_RELAXED, __HIP_MEMORY_SCOPE_AGENT);
    }
    // Drain own h stores to MALL, sync all waves, then publish padded flag.
    asm volatile("s_waitcnt vmcnt(0)" ::: "memory");
    __syncthreads();
    if (tid == 0)
      __hip_atomic_store(fOwn + wgl * FSTRIDE, t + 1, __ATOMIC_RELAXED, __HIP_MEMORY_SCOPE_AGENT);
  }
}

// ---------------- output projection driver (2 WGs x 64 o-columns) ----------------
__device__ __forceinline__ void run_out(
    int wgo, int tid,
    const unsigned short* __restrict__ h2base,
    const unsigned short* __restrict__ Wo,   // bf16 [128][1024] padded
    const float* __restrict__ bo,
    float* __restrict__ outp, float* gbuf, int* mb, int* fOwn, const int* fProd) {
  const int lane = tid & 63;
  const int w = tid >> 6;
  const int nl = lane & 15;
  const int kq8 = (lane >> 4) << 3;
  const int k0beg = w * 256;

  short8 bw[8][4];
#pragma unroll
  for (int ns = 0; ns < 4; ++ns) {
    int o = wgo * 64 + ns * 16 + nl;
    const unsigned short* wr = Wo + (size_t)o * HD + kq8 + k0beg;
#pragma unroll
    for (int k = 0; k < 8; ++k) bw[k][ns] = *(const short8*)(wr + k * 32);
  }

  const int aoff = ((k0beg >> 4) + (kq8 >> 4)) * 1024 + nl * 16 + (kq8 & 8);
  const int bb = (lane >> 4) << 2;
  float* gs = gbuf + w * 4096;

  for (int t = 0; t < TD; ++t) {
    if (w == 0) { wait1p(fProd, t + 1, lane); mb_store(mb + 0, t, lane); }
    else        { mb_spin(mb + 0, t); }
    if ((t & (NS - 1)) == 0) __builtin_amdgcn_fence(__ATOMIC_ACQUIRE, "agent");

    const unsigned short* arow = h2base + (size_t)(t & (NS - 1)) * BH + aoff;

    f32x4 acc[4][4];
    const f32x4 z4 = {0.f, 0.f, 0.f, 0.f};
#pragma unroll
    for (int ns = 0; ns < 4; ++ns)
#pragma unroll
      for (int mt = 0; mt < 4; ++mt) acc[ns][mt] = z4;

    gemm_bw<8>(arow, bw, acc);

#pragma unroll
    for (int ns = 0; ns < 4; ++ns) {
      int gn = ns * 16 + nl;
#pragma unroll
      for (int mt = 0; mt < 4; ++mt)
#pragma unroll
        for (int r = 0; r < 4; ++r)
          gs[sw(gn, mt * 16 + bb + r)] = acc[ns][mt][r];
    }
    __syncthreads();

#pragma unroll
    for (int it = 0; it < 16; ++it) {
      int item = it * 256 + tid;
      int ol = item >> 6;
      int b = item & 63;
      int o = wgo * 64 + ol;
      int a = sw(ol, b);
      float v = gbuf[a] + gbuf[4096 + a] + gbuf[8192 + a] + gbuf[12288 + a] + bo[o];
      if (o < 121) outp[((size_t)b * TD + t) * 121 + o] = v;
    }
    // A-reads of h2[t] fully retired (gemm drains to vmcnt 0) -> WAR signal.
    asm volatile("s_waitcnt vmcnt(0)" ::: "memory");
    __syncthreads();
    if (tid == 0)
      __hip_atomic_store(fOwn + wgo * FSTRIDE, t + 1, __ATOMIC_RELAXED, __HIP_MEMORY_SCOPE_AGENT);
  }
}

// ---------------- main kernel ----------------
// XCD-partitioned mapping (XCD = blockIdx%8): XCDs 0,1 -> layer0; 2,3 ->
// layer1; 4,5 -> layer2; XCD 6 slots 0,1 -> out-proj; rest exit.
// 256 blocks at 1 block/CU -> all co-resident regardless of actual mapping.
__global__ void __launch_bounds__(256, 1)
lstm_main(const float* __restrict__ strokes, const float* __restrict__ Wih0,
          float* __restrict__ outp, void* __restrict__ wsv) {
  __shared__ float gbuf[16384];  // 64 KB: 4 K-slices x [64 gn][64 b]
  __shared__ int mbx[2];         // LDS mailboxes (poller -> spinner)
  unsigned short* u = (unsigned short*)wsv;
  float* fr = (float*)((char*)wsv + FBYTE_BASE);
  int* flags = (int*)fr + FOFF_FLAGS;
  int* f0 = flags;               // layer0, padded (64 x FSTRIDE)
  int* f1 = flags + 2048;        // layer1
  int* f2 = flags + 4096;        // layer2
  int* f3 = flags + 6144;        // out (2 real + 62 preset huge)

  const int xcd = blockIdx.x & 7;
  const int slot = blockIdx.x >> 3;   // 0..31
  const int tid = threadIdx.x;

  if (tid == 0) { mbx[0] = -1; mbx[1] = -1; }
  __syncthreads();

  if (xcd < 2) {
    int wgl = ((xcd & 1) << 5) + slot;
    run_layer<true>(wgl, tid, nullptr, u + OFF_H0,
                    nullptr, u + OFF_WHH0, fr + FOFF_B0, strokes, Wih0, gbuf,
                    mbx, f0, nullptr, f1);
  } else if (xcd < 4) {
    int wgl = ((xcd & 1) << 5) + slot;
    run_layer<false>(wgl, tid, u + OFF_H0, u + OFF_H1,
                     u + OFF_WIH1, u + OFF_WHH1, fr + FOFF_B1, nullptr, nullptr, gbuf,
                     mbx, f1, f0, f2);
  } else if (xcd < 6) {
    int wgl = ((xcd & 1) << 5) + slot;
    run_layer<false>(wgl, tid, u + OFF_H1, u + OFF_H2,
                     u + OFF_WIH2, u + OFF_WHH2, fr + FOFF_B2, nullptr, nullptr, gbuf,
                     mbx, f2, f1, f3);
  } else if (xcd == 6 && slot < 2) {
    run_out(slot, tid, u + OFF_H2, u + OFF_WOUT, fr + FOFF_BOUT, outp, gbuf,
            mbx, f3, f2);
  }
  // else: idle block, exit immediately
}

extern "C" void kernel_launch(void* const* d_in, const int* in_sizes, int n_in,
                              void* d_out, int out_size, void* d_ws, size_t ws_size,
                              hipStream_t stream) {
  const float* strokes = (const float*)d_in[0];
  const float* Wih0 = (const float*)d_in[1];
  const float* Whh0 = (const float*)d_in[2];
  const float* bih0 = (const float*)d_in[3];
  const float* bhh0 = (const float*)d_in[4];
  const float* Wih1 = (const float*)d_in[5];
  const float* Whh1 = (const float*)d_in[6];
  const float* bih1 = (const float*)d_in[7];
  const float* bhh1 = (const float*)d_in[8];
  const float* Wih2 = (const float*)d_in[9];
  const float* Whh2 = (const float*)d_in[10];
  const float* bih2 = (const float*)d_in[11];
  const float* bhh2 = (const float*)d_in[12];
  const float* Wout = (const float*)d_in[13];
  const float* bout = (const float*)d_in[14];
  float* outp = (float*)d_out;

  hipLaunchKernelGGL(prep_kernel, dim3(4096), dim3(256), 0, stream,
                     Whh0, Wih1, Whh1, Wih2, Whh2, Wout,
                     bih0, bhh0, bih1, bhh1, bih2, bhh2, bout, d_ws);

  hipLaunchKernelGGL(lstm_main, dim3(NBLK), dim3(256), 0, stream,
                     strokes, Wih0, outp, d_ws);
}

// Round 10
// 3949.451 us; speedup vs baseline: 2.5643x; 1.3444x over previous
//
#include <hip/hip_runtime.h>

typedef __attribute__((ext_vector_type(8))) short short8;
typedef __attribute__((ext_vector_type(4))) float f32x4;
typedef __attribute__((ext_vector_type(4))) int int4v;

#define HD 1024
#define BD 64
#define TD 512
#define BH 65536UL  // one h slot: 64 wg x 64 b x 16 j ushorts (128 KB)
#define NS 16       // h slot rotation depth == fence period
#define NBLK 256    // 1 block/CU; XCD-partitioned mapping inside
#define FSTRIDE 32  // flag padding: 32 ints = 128 B = one line per WG

// ---------------- workspace layout (identical to R9) ----------------
#define M4 4194304UL
#define OFF_WHH0 0UL
#define OFF_WIH1 (1UL * M4)
#define OFF_WHH1 (2UL * M4)
#define OFF_WIH2 (3UL * M4)
#define OFF_WHH2 (4UL * M4)
#define OFF_WOUT (5UL * M4)                 // 128 x 1024 (padded rows zeroed)
#define OFF_H0   (OFF_WOUT + 131072UL)      // [NS][wg][b][16j] per layer (chunked)
#define OFF_H1   (OFF_H0 + (NS * BH))
#define OFF_H2   (OFF_H1 + (NS * BH))
#define USHORT_TOTAL (OFF_H2 + (NS * BH))   // 24248320
#define FBYTE_BASE (USHORT_TOTAL * 2UL)
#define FOFF_B0 196608UL                     // combined biases b_ih+b_hh [4096]
#define FOFF_B1 200704UL
#define FOFF_B2 204800UL
#define FOFF_BOUT 208896UL                   // [128], pad zeroed
#define FOFF_FLAGS 209024UL                  // 4 arrays x 64 WGs x FSTRIDE ints
#define PREP_TOTAL 24465536UL

__device__ __forceinline__ unsigned short f2bf(float f) {
  union { float f; unsigned u; } v; v.f = f;
  unsigned r = v.u + 0x7fffu + ((v.u >> 16) & 1u);  // RNE
  return (unsigned short)(r >> 16);
}
__device__ __forceinline__ float sigmoidf_(float x) {
  return 1.0f / (1.0f + __expf(-x));
}
// fast tanh via exp2-based __expf: tanh(x) = 1 - 2/(e^(2x)+1).
__device__ __forceinline__ float tanhf_(float x) {
  float e = __expf(x + x);
  return 1.0f - 2.0f / (e + 1.0f);
}
// LDS bank swizzle (unchanged).
__device__ __forceinline__ int sw(int gn, int b) {
  return gn * 64 + (b ^ (((gn & 7) << 2) | ((gn >> 3) & 3)));
}

// A-matrix load: plain cached 16B load (L2-served under the XCD partition).
// Coherence contract (HW-validated R4/R5/R6/R9): producers sc1-write-through h
// and drain vmcnt(0) before the relaxed flag store; NS=16 slot rotation + one
// acquire fence per 16-step window prevents stale cache lines.
__device__ __forceinline__ void gload16(int4v& dst, const unsigned short* p) {
  asm volatile("global_load_dwordx4 %0, %1, off" : "=v"(dst) : "v"(p));
}
#define AWAIT_N(N, a0, a1, a2, a3) \
  asm volatile("s_waitcnt vmcnt(" #N ")" : "+v"(a0), "+v"(a1), "+v"(a2), "+v"(a3))

// ---------------- padded per-WG progress flags (R6 scheme) ----------------
__device__ __forceinline__ void wait1p(const int* fa, int ka, int lane) {
  const int* pa = fa + lane * FSTRIDE;
  for (;;) {
    int va;
    asm volatile("global_load_dword %0, %1, off sc1" : "=v"(va) : "v"(pa));
    asm volatile("s_waitcnt vmcnt(0)" : "+v"(va));
    if (__all(va >= ka)) return;
    __builtin_amdgcn_s_sleep(1);   // recurrence-critical: minimal sleep
  }
}
__device__ __forceinline__ void wait2p(const int* fa, int ka, const int* fb, int kb, int lane) {
  const int* pa = fa + lane * FSTRIDE;
  const int* pb = fb + lane * FSTRIDE;
  for (;;) {
    int va, vb;
    asm volatile("global_load_dword %0, %1, off sc1" : "=v"(va) : "v"(pa));
    asm volatile("global_load_dword %0, %1, off sc1" : "=v"(vb) : "v"(pb));
    asm volatile("s_waitcnt vmcnt(0)" : "+v"(va), "+v"(vb));
    if (__all(va >= ka) && __all(vb >= kb)) return;
    __builtin_amdgcn_s_sleep(8);
  }
}
__device__ __forceinline__ void mb_store(int* m, int t, int lane) {
  if (lane == 0)
    __hip_atomic_store(m, t, __ATOMIC_RELEASE, __HIP_MEMORY_SCOPE_WORKGROUP);
}
__device__ __forceinline__ void mb_spin(const int* m, int t) {
  while (__hip_atomic_load(m, __ATOMIC_ACQUIRE, __HIP_MEMORY_SCOPE_WORKGROUP) < t)
    __builtin_amdgcn_s_sleep(1);
}

// ---------------- prep (identical byte layout to R9) ----------------
__global__ void prep_kernel(const float* __restrict__ Whh0, const float* __restrict__ Wih1,
                            const float* __restrict__ Whh1, const float* __restrict__ Wih2,
                            const float* __restrict__ Whh2, const float* __restrict__ Wout,
                            const float* __restrict__ bih0, const float* __restrict__ bhh0,
                            const float* __restrict__ bih1, const float* __restrict__ bhh1,
                            const float* __restrict__ bih2, const float* __restrict__ bhh2,
                            const float* __restrict__ bout, void* wsv) {
  unsigned short* u = (unsigned short*)wsv;
  float* fr = (float*)((char*)wsv + FBYTE_BASE);
  int* fi = (int*)fr;
  size_t stride = (size_t)gridDim.x * blockDim.x;
  for (size_t i = (size_t)blockIdx.x * blockDim.x + threadIdx.x; i < PREP_TOTAL; i += stride) {
    if (i < 20971520UL) {
      size_t which = i >> 22;
      size_t off = i & (M4 - 1UL);
      const float* src = (which == 0) ? Whh0 : (which == 1) ? Wih1 :
                         (which == 2) ? Whh1 : (which == 3) ? Wih2 : Whh2;
      u[i] = f2bf(src[off]);
    } else if (i < 21102592UL) {
      size_t k = i - 20971520UL;
      size_t o = k >> 10, kk = k & 1023UL;
      u[i] = (o < 121) ? f2bf(Wout[o * 1024UL + kk]) : (unsigned short)0;
    } else if (i < 24248320UL) {
      u[i] = 0;                                   // zero all NS h slots x 3 layers
    } else if (i < 24444928UL) {
      fr[i - 24248320UL] = 0.0f;                  // legacy c region (unused)
    } else if (i < 24457216UL) {
      size_t k = i - 24444928UL;
      size_t l = k >> 12, n = k & 4095UL;
      const float* bi = (l == 0) ? bih0 : (l == 1) ? bih1 : bih2;
      const float* bh = (l == 0) ? bhh0 : (l == 1) ? bhh1 : bhh2;
      fr[FOFF_B0 + l * 4096UL + n] = bi[n] + bh[n];
    } else if (i < 24457344UL) {
      size_t k = i - 24457216UL;
      fr[FOFF_BOUT + k] = (k < 121) ? bout[k] : 0.0f;
    } else {
      size_t k = i - 24457344UL;                  // 8192 padded flag ints
      size_t a = k >> 11;                         // array 0..3
      size_t wg = (k & 2047UL) >> 5;              // WG slot within array
      fi[FOFF_FLAGS + k] = (a < 3 || wg < 2) ? 0 : (1 << 29);
    }
  }
}

// ---------------- GEMM slice over CHUNKED h: [wg][b][16j] ----------------
template <int NK>
__device__ __forceinline__ void gemm_bw(const unsigned short* __restrict__ arow,
                                        const short8 (&bw)[NK][4],
                                        f32x4 (&acc)[4][4]) {
  static_assert(NK >= 6, "pipeline depth");
  int4v ap[6][4];
#pragma unroll
  for (int g = 0; g < 6; ++g)
#pragma unroll
    for (int mt = 0; mt < 4; ++mt)
      gload16(ap[g][mt], arow + mt * 256 + g * 2048);
#pragma unroll
  for (int k = 0; k < NK; ++k) {
    const int s = k % 6;
    if (k <= NK - 6)          { AWAIT_N(20, ap[s][0], ap[s][1], ap[s][2], ap[s][3]); }
    else if (NK - 1 - k == 4) { AWAIT_N(16, ap[s][0], ap[s][1], ap[s][2], ap[s][3]); }
    else if (NK - 1 - k == 3) { AWAIT_N(12, ap[s][0], ap[s][1], ap[s][2], ap[s][3]); }
    else if (NK - 1 - k == 2) { AWAIT_N(8,  ap[s][0], ap[s][1], ap[s][2], ap[s][3]); }
    else if (NK - 1 - k == 1) { AWAIT_N(4,  ap[s][0], ap[s][1], ap[s][2], ap[s][3]); }
    else                      { AWAIT_N(0,  ap[s][0], ap[s][1], ap[s][2], ap[s][3]); }
#pragma unroll
    for (int mt = 0; mt < 4; ++mt) {
      short8 a = *(short8*)&ap[s][mt];
#pragma unroll
      for (int ns = 0; ns < 4; ++ns)
        acc[ns][mt] = __builtin_amdgcn_mfma_f32_16x16x32_bf16(a, bw[k][ns], acc[ns][mt], 0, 0, 0);
    }
    if (k + 6 < NK) {
#pragma unroll
      for (int mt = 0; mt < 4; ++mt)
        gload16(ap[s][mt], arow + mt * 256 + (k + 6) * 2048);
    }
  }
}

// ---------------- persistent-weight layer driver ----------------
// R9 structure + wave-contiguous epilogue: thread handles b = w*16+(lane>>2),
// j-quad jq = lane&3 -> ONE 8B store at ushort offset wgl*1024 + w*256 + lane*4.
// Consecutive lanes -> consecutive 8B -> 512B contiguous per wave -> full-line
// write-combine at MALL (kills the 8x partial-line RMW amplification).
template <bool L0L>
__device__ __forceinline__ void run_layer(
    int wgl, int tid,
    const unsigned short* __restrict__ hinbase,  // upstream h (NS slots), null for L0
    unsigned short* __restrict__ hbase,          // own h (NS slots)
    const unsigned short* __restrict__ Wih,      // null for L0
    const unsigned short* __restrict__ Whh,
    const float* __restrict__ bias,
    const float* __restrict__ strokes,           // L0 only
    const float* __restrict__ Wih0,              // L0 only, fp32 [4096][3]
    float* gbuf, int* mb, int* fOwn, const int* fProd, const int* fCons) {
  constexpr int NK = L0L ? 8 : 16;
  const int lane = tid & 63;
  const int w = tid >> 6;
  const int nl = lane & 15;
  const int kq8 = (lane >> 4) << 3;

  const unsigned short* Wm;
  int k0beg;
  bool useHin;
  if (L0L) { Wm = Whh; k0beg = w * 256; useHin = false; }
  else     { Wm = (w < 2) ? Wih : Whh; k0beg = (w & 1) * 512; useHin = (w < 2); }

  short8 bw[NK][4];
#pragma unroll
  for (int ns = 0; ns < 4; ++ns) {
    int jgl = wgl * 16 + ns * 4 + (nl >> 2);
    int row = (nl & 3) * HD + jgl;                 // gate-major weight row
    const unsigned short* wr = Wm + (size_t)row * HD + kq8 + k0beg;
#pragma unroll
    for (int k = 0; k < NK; ++k) bw[k][ns] = *(const short8*)(wr + k * 32);
  }

  // per-lane chunked-A base offset (ushorts)
  const int aoff = ((k0beg >> 4) + (kq8 >> 4)) * 1024 + nl * 16 + (kq8 & 8);

  const int bb = (lane >> 4) << 2;
  float* gs = gbuf + w * 4096;

  // epilogue mapping: this thread's batch row + j-quad (fixed across t)
  const int eb = (w << 4) + (lane >> 2);
  const int ejq = lane & 3;
  // c state: thread-private, fixed (j,b) across t -> pure registers.
  float cr[4] = {0.f, 0.f, 0.f, 0.f};

  for (int t = 0; t < TD; ++t) {
    // ---- sync: 2 global pollers + 2 LDS spinners (R6 scheme) ----
    if (L0L) {
      if (t > 0) {
        if (w == 0)      { wait2p(fOwn, t, fCons, t - (NS - 1), lane); mb_store(mb + 0, t, lane); }
        else if (w == 1) { mb_spin(mb + 0, t); }
        else if (w == 2) { wait1p(fOwn, t, lane); mb_store(mb + 1, t, lane); }
        else             { mb_spin(mb + 1, t); }
      }
    } else {
      if (w == 0) {
        if (t > 0) wait2p(fProd, t + 1, fCons, t - (NS - 1), lane);
        else       wait1p(fProd, 1, lane);
        mb_store(mb + 0, t, lane);
      } else if (w == 1) {
        mb_spin(mb + 0, t);
      } else if (w == 2) {
        if (t > 0) { wait1p(fOwn, t, lane); mb_store(mb + 1, t, lane); }
      } else {
        if (t > 0) mb_spin(mb + 1, t);
      }
    }
    // Slot-reuse invalidate, once per NS steps.
    if ((t & (NS - 1)) == 0) __builtin_amdgcn_fence(__ATOMIC_ACQUIRE, "agent");

    const unsigned short* A = useHin ? (hinbase + (size_t)(t & (NS - 1)) * BH)
                                     : (hbase + (size_t)((t - 1) & (NS - 1)) * BH);
    const unsigned short* arow = A + aoff;

    f32x4 acc[4][4];
    const f32x4 z4 = {0.f, 0.f, 0.f, 0.f};
#pragma unroll
    for (int ns = 0; ns < 4; ++ns)
#pragma unroll
      for (int mt = 0; mt < 4; ++mt) acc[ns][mt] = z4;

    gemm_bw<NK>(arow, bw, acc);

#pragma unroll
    for (int ns = 0; ns < 4; ++ns) {
      int gn = ns * 16 + nl;
#pragma unroll
      for (int mt = 0; mt < 4; ++mt)
#pragma unroll
        for (int r = 0; r < 4; ++r)
          gs[sw(gn, mt * 16 + bb + r)] = acc[ns][mt][r];
    }
    __syncthreads();  // gbuf ready; also orders h-stores after w0's WAR check

    // ---- epilogue: 4 j's for one b; single coalesced 8B store ----
    unsigned short* hout = hbase + (size_t)(t & (NS - 1)) * BH;
    float x0 = 0.f, x1 = 0.f, x2 = 0.f;
    if (L0L) {
      const float* xr = strokes + ((size_t)eb * TD + t) * 3;
      x0 = xr[0]; x1 = xr[1]; x2 = xr[2];
    }
    unsigned short hv4[4];
#pragma unroll
    for (int u = 0; u < 4; ++u) {
      int jj = ejq * 4 + u;
      int j = wgl * 16 + jj;
      float p[4];
#pragma unroll
      for (int g = 0; g < 4; ++g) {
        int a = sw(jj * 4 + g, eb);
        p[g] = gbuf[a] + gbuf[4096 + a] + gbuf[8192 + a] + gbuf[12288 + a] + bias[g * HD + j];
      }
      if (L0L) {
#pragma unroll
        for (int g = 0; g < 4; ++g) {
          const float* wr = Wih0 + (size_t)(g * HD + j) * 3;
          p[g] += x0 * wr[0] + x1 * wr[1] + x2 * wr[2];
        }
      }
      float iv = sigmoidf_(p[0]);
      float fv = sigmoidf_(p[1]);
      float gv = tanhf_(p[2]);
      float ov = sigmoidf_(p[3]);
      float cn = fv * cr[u] + iv * gv;
      cr[u] = cn;
      hv4[u] = f2bf(ov * tanhf_(cn));
    }
    unsigned long long pk =
        (unsigned long long)((unsigned)hv4[0] | ((unsigned)hv4[1] << 16)) |
        ((unsigned long long)((unsigned)hv4[2] | ((unsigned)hv4[3] << 16)) << 32);
    // chunked layout [wg][b][16j]: lane-contiguous 8B -> 512B/wave contiguous.
    __hip_atomic_store((unsigned long long*)(hout + (size_t)wgl * 1024 + eb * 16 + ejq * 4),
                       pk, __ATOMIC_RELAXED, __HIP_MEMORY_SCOPE_AGENT);

    // Drain own h stores to MALL, sync all waves, then publish padded flag.
    asm volatile("s_waitcnt vmcnt(0)" ::: "memory");
    __syncthreads();
    if (tid == 0)
      __hip_atomic_store(fOwn + wgl * FSTRIDE, t + 1, __ATOMIC_RELAXED, __HIP_MEMORY_SCOPE_AGENT);
  }
}

// ---------------- output projection driver (2 WGs x 64 o-columns) ----------------
__device__ __forceinline__ void run_out(
    int wgo, int tid,
    const unsigned short* __restrict__ h2base,
    const unsigned short* __restrict__ Wo,   // bf16 [128][1024] padded
    const float* __restrict__ bo,
    float* __restrict__ outp, float* gbuf, int* mb, int* fOwn, const int* fProd) {
  const int lane = tid & 63;
  const int w = tid >> 6;
  const int nl = lane & 15;
  const int kq8 = (lane >> 4) << 3;
  const int k0beg = w * 256;

  short8 bw[8][4];
#pragma unroll
  for (int ns = 0; ns < 4; ++ns) {
    int o = wgo * 64 + ns * 16 + nl;
    const unsigned short* wr = Wo + (size_t)o * HD + kq8 + k0beg;
#pragma unroll
    for (int k = 0; k < 8; ++k) bw[k][ns] = *(const short8*)(wr + k * 32);
  }

  const int aoff = ((k0beg >> 4) + (kq8 >> 4)) * 1024 + nl * 16 + (kq8 & 8);
  const int bb = (lane >> 4) << 2;
  float* gs = gbuf + w * 4096;

  for (int t = 0; t < TD; ++t) {
    if (w == 0) { wait1p(fProd, t + 1, lane); mb_store(mb + 0, t, lane); }
    else        { mb_spin(mb + 0, t); }
    if ((t & (NS - 1)) == 0) __builtin_amdgcn_fence(__ATOMIC_ACQUIRE, "agent");

    const unsigned short* arow = h2base + (size_t)(t & (NS - 1)) * BH + aoff;

    f32x4 acc[4][4];
    const f32x4 z4 = {0.f, 0.f, 0.f, 0.f};
#pragma unroll
    for (int ns = 0; ns < 4; ++ns)
#pragma unroll
      for (int mt = 0; mt < 4; ++mt) acc[ns][mt] = z4;

    gemm_bw<8>(arow, bw, acc);

#pragma unroll
    for (int ns = 0; ns < 4; ++ns) {
      int gn = ns * 16 + nl;
#pragma unroll
      for (int mt = 0; mt < 4; ++mt)
#pragma unroll
        for (int r = 0; r < 4; ++r)
          gs[sw(gn, mt * 16 + bb + r)] = acc[ns][mt][r];
    }
    __syncthreads();

#pragma unroll
    for (int it = 0; it < 16; ++it) {
      int item = it * 256 + tid;
      int ol = item >> 6;
      int b = item & 63;
      int o = wgo * 64 + ol;
      int a = sw(ol, b);
      float v = gbuf[a] + gbuf[4096 + a] + gbuf[8192 + a] + gbuf[12288 + a] + bo[o];
      if (o < 121) outp[((size_t)b * TD + t) * 121 + o] = v;
    }
    // A-reads of h2[t] fully retired (gemm drains to vmcnt 0) -> WAR signal.
    asm volatile("s_waitcnt vmcnt(0)" ::: "memory");
    __syncthreads();
    if (tid == 0)
      __hip_atomic_store(fOwn + wgo * FSTRIDE, t + 1, __ATOMIC_RELAXED, __HIP_MEMORY_SCOPE_AGENT);
  }
}

// ---------------- main kernel ----------------
// XCD-partitioned mapping (XCD = blockIdx%8): XCDs 0,1 -> layer0; 2,3 ->
// layer1; 4,5 -> layer2; XCD 6 slots 0,1 -> out-proj; rest exit.
// 256 blocks at 1 block/CU -> all co-resident regardless of actual mapping.
__global__ void __launch_bounds__(256, 1)
lstm_main(const float* __restrict__ strokes, const float* __restrict__ Wih0,
          float* __restrict__ outp, void* __restrict__ wsv) {
  __shared__ float gbuf[16384];  // 64 KB: 4 K-slices x [64 gn][64 b]
  __shared__ int mbx[2];         // LDS mailboxes (poller -> spinner)
  unsigned short* u = (unsigned short*)wsv;
  float* fr = (float*)((char*)wsv + FBYTE_BASE);
  int* flags = (int*)fr + FOFF_FLAGS;
  int* f0 = flags;               // layer0, padded (64 x FSTRIDE)
  int* f1 = flags + 2048;        // layer1
  int* f2 = flags + 4096;        // layer2
  int* f3 = flags + 6144;        // out (2 real + 62 preset huge)

  const int xcd = blockIdx.x & 7;
  const int slot = blockIdx.x >> 3;   // 0..31
  const int tid = threadIdx.x;

  if (tid == 0) { mbx[0] = -1; mbx[1] = -1; }
  __syncthreads();

  if (xcd < 2) {
    int wgl = ((xcd & 1) << 5) + slot;
    run_layer<true>(wgl, tid, nullptr, u + OFF_H0,
                    nullptr, u + OFF_WHH0, fr + FOFF_B0, strokes, Wih0, gbuf,
                    mbx, f0, nullptr, f1);
  } else if (xcd < 4) {
    int wgl = ((xcd & 1) << 5) + slot;
    run_layer<false>(wgl, tid, u + OFF_H0, u + OFF_H1,
                     u + OFF_WIH1, u + OFF_WHH1, fr + FOFF_B1, nullptr, nullptr, gbuf,
                     mbx, f1, f0, f2);
  } else if (xcd < 6) {
    int wgl = ((xcd & 1) << 5) + slot;
    run_layer<false>(wgl, tid, u + OFF_H1, u + OFF_H2,
                     u + OFF_WIH2, u + OFF_WHH2, fr + FOFF_B2, nullptr, nullptr, gbuf,
                     mbx, f2, f1, f3);
  } else if (xcd == 6 && slot < 2) {
    run_out(slot, tid, u + OFF_H2, u + OFF_WOUT, fr + FOFF_BOUT, outp, gbuf,
            mbx, f3, f2);
  }
  // else: idle block, exit immediately
}

extern "C" void kernel_launch(void* const* d_in, const int* in_sizes, int n_in,
                              void* d_out, int out_size, void* d_ws, size_t ws_size,
                              hipStream_t stream) {
  const float* strokes = (const float*)d_in[0];
  const float* Wih0 = (const float*)d_in[1];
  const float* Whh0 = (const float*)d_in[2];
  const float* bih0 = (const float*)d_in[3];
  const float* bhh0 = (const float*)d_in[4];
  const float* Wih1 = (const float*)d_in[5];
  const float* Whh1 = (const float*)d_in[6];
  const float* bih1 = (const float*)d_in[7];
  const float* bhh1 = (const float*)d_in[8];
  const float* Wih2 = (const float*)d_in[9];
  const float* Whh2 = (const float*)d_in[10];
  const float* bih2 = (const float*)d_in[11];
  const float* bhh2 = (const float*)d_in[12];
  const float* Wout = (const float*)d_in[13];
  const float* bout = (const float*)d_in[14];
  float* outp = (float*)d_out;

  hipLaunchKernelGGL(prep_kernel, dim3(4096), dim3(256), 0, stream,
                     Whh0, Wih1, Whh1, Wih2, Whh2, Wout,
                     bih0, bhh0, bih1, bhh1, bih2, bhh2, bout, d_ws);

  hipLaunchKernelGGL(lstm_main, dim3(NBLK), dim3(256), 0, stream,
                     strokes, Wih0, outp, d_ws);
}